// Round 12
// baseline (570.174 us; speedup 1.0000x reference)
//
#include <hip/hip_runtime.h>
#include <math.h>

#pragma clang fp contract(off)

#define VV 5
#define BB 2
#define CC 32
#define HH 128
#define WW 128
#define DD 32
#define GG 8
#define HWW (HH*WW)
#define TRBLOCKS (VV*BB*(HWW/64))   // 2560 transpose blocks

// ---------------------------------------------------------------------------
// Kernel 1 (fused): transpose features [VB,C,H,W] -> [VB,H,W,C]  +  proj setup.
// (kept from r11 — bit-exact copy; proj math bit-frozen at r9)
// ---------------------------------------------------------------------------
__global__ __launch_bounds__(256) void prep_kernel(const float* __restrict__ fea,
                                                   float* __restrict__ featT,
                                                   const float* __restrict__ pm,
                                                   float* __restrict__ wproj) {
#pragma clang fp contract(off)
    int t = threadIdx.x;
    if (blockIdx.x == TRBLOCKS) {
        int tid = t;
        if (tid >= BB * (VV - 1)) return;
        int b = tid / (VV - 1);
        int v = tid % (VV - 1) + 1;

        float refP[4][4], srcP[4][4];
        for (int which = 0; which < 2; which++) {
            int view = (which == 0) ? 0 : v;
            const float* base = pm + (size_t)(b * VV + view) * 2 * 16;
            const float* ext  = base;
            const float* intr = base + 16;
            float (*M)[4] = (which == 0) ? refP : srcP;
            for (int r = 0; r < 3; r++)
                for (int c = 0; c < 4; c++) {
                    float s = 0.f;
                    for (int k = 0; k < 3; k++)
                        s = fmaf(intr[r * 4 + k], ext[k * 4 + c], s);  // einsum FMA chain
                    M[r][c] = s;
                }
            for (int c = 0; c < 4; c++) M[3][c] = ext[12 + c];
        }

        float A[4][4];
        for (int r = 0; r < 4; r++)
            for (int c = 0; c < 4; c++) A[r][c] = refP[r][c];
        int ipiv[4];
        for (int j = 0; j < 4; j++) {
            int p = j; float amax = fabsf(A[j][j]);
            for (int i = j + 1; i < 4; i++) {
                float tt = fabsf(A[i][j]);
                if (tt > amax) { amax = tt; p = i; }
            }
            ipiv[j] = p;
            if (p != j)
                for (int c = 0; c < 4; c++) { float tt = A[j][c]; A[j][c] = A[p][c]; A[p][c] = tt; }
            float rcp = 1.0f / A[j][j];
            for (int i = j + 1; i < 4; i++) A[i][j] = A[i][j] * rcp;
            for (int i = j + 1; i < 4; i++)
                for (int k = j + 1; k < 4; k++)
                    A[i][k] = fmaf(-A[i][j], A[j][k], A[i][k]);
        }

        float Bm[4][4];
        for (int r = 0; r < 4; r++)
            for (int c = 0; c < 4; c++) Bm[r][c] = (r == c) ? 1.f : 0.f;
        for (int j = 0; j < 4; j++) {
            int p = ipiv[j];
            if (p != j)
                for (int c = 0; c < 4; c++) { float tt = Bm[j][c]; Bm[j][c] = Bm[p][c]; Bm[p][c] = tt; }
        }
        float invd[4];
        for (int k = 0; k < 4; k++) invd[k] = 1.0f / A[k][k];
        for (int c = 0; c < 4; c++) {
            for (int k = 0; k < 4; k++)
                for (int i = k + 1; i < 4; i++)
                    Bm[i][c] = fmaf(-A[i][k], Bm[k][c], Bm[i][c]);
            for (int k = 3; k >= 0; k--) {
                Bm[k][c] = Bm[k][c] * invd[k];
                for (int i = 0; i < k; i++)
                    Bm[i][c] = fmaf(-A[i][k], Bm[k][c], Bm[i][c]);
            }
        }

        float P[3][4];
        for (int r = 0; r < 3; r++)
            for (int c = 0; c < 4; c++) {
                float s = 0.f;
                for (int k = 0; k < 4; k++)
                    s = fmaf(srcP[r][k], Bm[k][c], s);
                P[r][c] = s;
            }
        float* o = wproj + (b * (VV - 1) + (v - 1)) * 12;
        for (int r = 0; r < 3; r++)
            for (int c = 0; c < 3; c++) o[r * 3 + c] = P[r][c];
        for (int r = 0; r < 3; r++) o[9 + r] = P[r][3];
        return;
    }

    __shared__ float tile[64][36];
    int vb = blockIdx.x >> 8;
    int base = (blockIdx.x & 255) * 64;
#pragma unroll
    for (int k = 0; k < 2; k++) {
        int c = (t >> 4) + 16 * k;
        int p = t & 15;
        float4 v = *(const float4*)&fea[((size_t)vb * CC + c) * HWW + base + 4 * p];
        int cs = c ^ ((p & 7) << 2);
        tile[4 * p + 0][cs] = v.x;
        tile[4 * p + 1][cs] = v.y;
        tile[4 * p + 2][cs] = v.z;
        tile[4 * p + 3][cs] = v.w;
    }
    __syncthreads();
#pragma unroll
    for (int m = 0; m < 2; m++) {
        int pl = (t >> 3) + 32 * m;
        int q = t & 7;
        int sw = ((pl >> 2) & 7) << 2;
        float4 v = *(const float4*)&tile[pl][(4 * q) ^ sw];
        *(float4*)&featT[((size_t)vb * HWW + base + pl) * CC + 4 * q] = v;
    }
}

// ---------------------------------------------------------------------------
// Kernel 2: fused pipeline, arithmetic BIT-FROZEN at r9/r10. Perf changes:
//  - ref fragment re-read from LDS inside the group loop (opaque offset stops
//    hoisting) -> frees 32 VGPRs that were pinned across the kernel
//  - __launch_bounds__(256,8) pins allocator at <=64 VGPR -> 8 waves/SIMD
//  - single s_e buffer, no forced unroll (r10 config)
// ---------------------------------------------------------------------------
__global__ __launch_bounds__(256, 8) void main_kernel(const float* __restrict__ featT,
                                                      const float* __restrict__ wproj,
                                                      const float* __restrict__ depth_hypo,
                                                      const float* __restrict__ reg_w,
                                                      float* __restrict__ out) {
#pragma clang fp contract(off)
    __shared__ float s_ref[8][32];
    __shared__ float s_e[8][32];
    __shared__ float s_proj[4][12];
    __shared__ float s_regw[8];

    int t = threadIdx.x;
    int d = t & 31, pl = t >> 5;
    int base = t & 32;
    int pixbase = blockIdx.x * 8;
    int b = pixbase / HWW;
    int hwb = pixbase - b * HWW;

    s_ref[pl][d] = featT[((size_t)(b * HWW + hwb + pl)) * CC + d];
    if (t < 48) s_proj[t / 12][t % 12] = wproj[b * (VV - 1) * 12 + t];
    if (t < 8) s_regw[t] = reg_w[t];
    __syncthreads();

    int hw = hwb + pl;
    int y = hw >> 7, x = hw & (WW - 1);
    float fx = (float)x, fy = (float)y;
    float dep = depth_hypo[(size_t)(b * DD + d) * HWW + hw];

    // opaque zero: compiler cannot prove loop-invariance of LDS reads using it
    int off0 = 0;
    asm volatile("" : "+v"(off0));

    float accs[8];
#pragma unroll
    for (int g = 0; g < 8; g++) accs[g] = 0.f;
    float cws = 1e-8f;

    for (int vi = 0; vi < 4; vi++) {
        const float* pr = s_proj[vi];
        float rx = fmaf(pr[1], fy, pr[0] * fx) + pr[2];
        float ry = fmaf(pr[4], fy, pr[3] * fx) + pr[5];
        float rz = fmaf(pr[7], fy, pr[6] * fx) + pr[8];
        float X = rx * dep + pr[9];
        float Y = ry * dep + pr[10];
        float Z = rz * dep + pr[11];
        if (Z == 0.f) Z = 1e-9f;
        float px = X / Z, py = Y / Z;

        float x0f = floorf(px), y0f = floorf(py);
        float x1f = x0f + 1.0f, y1f = y0f + 1.0f;
        float wx1 = px - x0f, wx0 = 1.0f - wx1;
        float wy1 = py - y0f, wy0 = 1.0f - wy1;
        bool vx0 = (x0f >= 0.f) && (x0f <= (float)(WW - 1));
        bool vx1 = (x1f >= 0.f) && (x1f <= (float)(WW - 1));
        bool vy0 = (y0f >= 0.f) && (y0f <= (float)(HH - 1));
        bool vy1 = (y1f >= 0.f) && (y1f <= (float)(HH - 1));

        int xc0 = (int)fminf(fmaxf(x0f, 0.f), (float)(WW - 1));
        int xc1 = (int)fminf(fmaxf(x1f, 0.f), (float)(WW - 1));
        int yc0 = (int)fminf(fmaxf(y0f, 0.f), (float)(HH - 1));
        int yc1 = (int)fminf(fmaxf(y1f, 0.f), (float)(HH - 1));

        float w00 = (wx0 * wy0) * ((vx0 && vy0) ? 1.f : 0.f);
        float w10 = (wx1 * wy0) * ((vx1 && vy0) ? 1.f : 0.f);
        float w01 = (wx0 * wy1) * ((vx0 && vy1) ? 1.f : 0.f);
        float w11 = (wx1 * wy1) * ((vx1 && vy1) ? 1.f : 0.f);

        const float* srcB = featT + (size_t)((vi + 1) * BB + b) * HWW * CC;
        const float4* p00 = (const float4*)(srcB + ((size_t)yc0 * WW + xc0) * CC);
        const float4* p10 = (const float4*)(srcB + ((size_t)yc0 * WW + xc1) * CC);
        const float4* p01 = (const float4*)(srcB + ((size_t)yc1 * WW + xc0) * CC);
        const float4* p11 = (const float4*)(srcB + ((size_t)yc1 * WW + xc1) * CC);

        float cf[8];
        float s = 0.f;
#pragma unroll
        for (int g = 0; g < 8; g++) {
            float4 rf = *(const float4*)&s_ref[pl][g * 4 + off0];   // LDS re-read
            float4 f00 = p00[g], f10 = p10[g], f01 = p01[g], f11 = p11[g];
            float wrp[4];
            {
                float a;
                a = f00.x * w00; a = a + f10.x * w10; a = a + f01.x * w01; a = a + f11.x * w11; wrp[0] = a;
                a = f00.y * w00; a = a + f10.y * w10; a = a + f01.y * w01; a = a + f11.y * w11; wrp[1] = a;
                a = f00.z * w00; a = a + f10.z * w10; a = a + f01.z * w01; a = a + f11.z * w11; wrp[2] = a;
                a = f00.w * w00; a = a + f10.w * w10; a = a + f01.w * w01; a = a + f11.w * w11; wrp[3] = a;
            }
            float pr0 = wrp[0] * rf.x;
            float pr1 = wrp[1] * rf.y;
            float pr2 = wrp[2] * rf.z;
            float pr3 = wrp[3] * rf.w;
            float gs = pr0;
            gs = gs + pr1; gs = gs + pr2; gs = gs + pr3;
            gs = gs * 0.25f;
            cf[g] = gs;
            s = s + gs;
        }

        // softmax over d: max butterfly (order-free), denominator via LDS
        // round-trip + SAME sequential d-order adds (bit-identical).
        float m = s;
#pragma unroll
        for (int msk = 1; msk < 32; msk <<= 1) m = fmaxf(m, __shfl_xor(m, msk, 64));
        float e = expf(s - m);
        s_e[pl][d] = e;
        float sum = 0.f;
#pragma unroll
        for (int j = 0; j < 8; j++) {
            float4 q = *(const float4*)&s_e[pl][j * 4 + off0];
            sum = sum + q.x; sum = sum + q.y; sum = sum + q.z; sum = sum + q.w;
        }
        float cw = (e / sum) * 0.17677669529663687f;

        cws = cws + cw;
#pragma unroll
        for (int g = 0; g < 8; g++) {
            float tterm = cw * cf[g];
            accs[g] = accs[g] + tterm;
        }
    }

    // logit: elementwise /cws then einsum FMA chain over g
    float logit = 0.f;
#pragma unroll
    for (int g = 0; g < 8; g++) {
        float cfn = accs[g] / cws;
        logit = fmaf(s_regw[g], cfn, logit);
    }

    // final softmax over d (same LDS pattern)
    float m2 = logit;
#pragma unroll
    for (int msk = 1; msk < 32; msk <<= 1) m2 = fmaxf(m2, __shfl_xor(m2, msk, 64));
    float e2 = expf(logit - m2);
    s_e[pl][d] = e2;
    float s2 = 0.f;
#pragma unroll
    for (int j = 0; j < 8; j++) {
        float4 q = *(const float4*)&s_e[pl][j * 4 + off0];
        s2 = s2 + q.x; s2 = s2 + q.y; s2 = s2 + q.z; s2 = s2 + q.w;
    }
    float attn = e2 / s2;
    out[(size_t)BB * HWW + (size_t)(b * DD + d) * HWW + hw] = attn;

    // np.argmax: bitwise max (butterfly) + min lane holding it
    float a1 = attn;
#pragma unroll
    for (int msk = 1; msk < 32; msk <<= 1) a1 = fmaxf(a1, __shfl_xor(a1, msk, 64));
    int idx1 = (attn == a1) ? d : 1000;
#pragma unroll
    for (int msk = 1; msk < 32; msk <<= 1) {
        int oi = __shfl_xor(idx1, msk, 64);
        idx1 = (oi < idx1) ? oi : idx1;
    }
    float dep1 = __shfl(dep, base + idx1, 64);
    if (d == 0) out[b * HWW + hw] = dep1;
}

// ---------------------------------------------------------------------------
extern "C" void kernel_launch(void* const* d_in, const int* in_sizes, int n_in,
                              void* d_out, int out_size, void* d_ws, size_t ws_size,
                              hipStream_t stream) {
    const float* features   = (const float*)d_in[0];   // [V,B,C,H,W]
    const float* pm         = (const float*)d_in[1];   // [B,V,2,4,4]
    const float* depth_hypo = (const float*)d_in[2];   // [B,D,H,W]
    const float* reg_w      = (const float*)d_in[3];   // [G]
    float* out = (float*)d_out;                        // depth [B,H,W] ++ attn [B,D,H,W]

    float* wproj = (float*)d_ws;                       // 96 floats
    float* featT = (float*)((char*)d_ws + 4096);       // [VB,H,W,C] = 21 MB

    prep_kernel<<<TRBLOCKS + 1, 256, 0, stream>>>(features, featT, pm, wproj);
    main_kernel<<<BB * HWW / 8, 256, 0, stream>>>(featT, wproj, depth_hypo, reg_w, out);
}

// Round 13
// 156.608 us; speedup vs baseline: 3.6408x; 3.6408x over previous
//
#include <hip/hip_runtime.h>
#include <math.h>

#pragma clang fp contract(off)

#define VV 5
#define BB 2
#define CC 32
#define HH 128
#define WW 128
#define DD 32
#define GG 8
#define HWW (HH*WW)
#define TRBLOCKS (VV*BB*(HWW/64))   // 2560 transpose blocks

// ---------------------------------------------------------------------------
// Kernel 1 (fused): transpose features [VB,C,H,W] -> [VB,H,W,C]  +  proj setup.
// (unchanged from r10/r11 — bit-exact copy; proj math bit-frozen at r9)
// ---------------------------------------------------------------------------
__global__ __launch_bounds__(256) void prep_kernel(const float* __restrict__ fea,
                                                   float* __restrict__ featT,
                                                   const float* __restrict__ pm,
                                                   float* __restrict__ wproj) {
#pragma clang fp contract(off)
    int t = threadIdx.x;
    if (blockIdx.x == TRBLOCKS) {
        int tid = t;
        if (tid >= BB * (VV - 1)) return;
        int b = tid / (VV - 1);
        int v = tid % (VV - 1) + 1;

        float refP[4][4], srcP[4][4];
        for (int which = 0; which < 2; which++) {
            int view = (which == 0) ? 0 : v;
            const float* base = pm + (size_t)(b * VV + view) * 2 * 16;
            const float* ext  = base;
            const float* intr = base + 16;
            float (*M)[4] = (which == 0) ? refP : srcP;
            for (int r = 0; r < 3; r++)
                for (int c = 0; c < 4; c++) {
                    float s = 0.f;
                    for (int k = 0; k < 3; k++)
                        s = fmaf(intr[r * 4 + k], ext[k * 4 + c], s);  // einsum FMA chain
                    M[r][c] = s;
                }
            for (int c = 0; c < 4; c++) M[3][c] = ext[12 + c];
        }

        float A[4][4];
        for (int r = 0; r < 4; r++)
            for (int c = 0; c < 4; c++) A[r][c] = refP[r][c];
        int ipiv[4];
        for (int j = 0; j < 4; j++) {
            int p = j; float amax = fabsf(A[j][j]);
            for (int i = j + 1; i < 4; i++) {
                float tt = fabsf(A[i][j]);
                if (tt > amax) { amax = tt; p = i; }
            }
            ipiv[j] = p;
            if (p != j)
                for (int c = 0; c < 4; c++) { float tt = A[j][c]; A[j][c] = A[p][c]; A[p][c] = tt; }
            float rcp = 1.0f / A[j][j];
            for (int i = j + 1; i < 4; i++) A[i][j] = A[i][j] * rcp;
            for (int i = j + 1; i < 4; i++)
                for (int k = j + 1; k < 4; k++)
                    A[i][k] = fmaf(-A[i][j], A[j][k], A[i][k]);
        }

        float Bm[4][4];
        for (int r = 0; r < 4; r++)
            for (int c = 0; c < 4; c++) Bm[r][c] = (r == c) ? 1.f : 0.f;
        for (int j = 0; j < 4; j++) {
            int p = ipiv[j];
            if (p != j)
                for (int c = 0; c < 4; c++) { float tt = Bm[j][c]; Bm[j][c] = Bm[p][c]; Bm[p][c] = tt; }
        }
        float invd[4];
        for (int k = 0; k < 4; k++) invd[k] = 1.0f / A[k][k];
        for (int c = 0; c < 4; c++) {
            for (int k = 0; k < 4; k++)
                for (int i = k + 1; i < 4; i++)
                    Bm[i][c] = fmaf(-A[i][k], Bm[k][c], Bm[i][c]);
            for (int k = 3; k >= 0; k--) {
                Bm[k][c] = Bm[k][c] * invd[k];
                for (int i = 0; i < k; i++)
                    Bm[i][c] = fmaf(-A[i][k], Bm[k][c], Bm[i][c]);
            }
        }

        float P[3][4];
        for (int r = 0; r < 3; r++)
            for (int c = 0; c < 4; c++) {
                float s = 0.f;
                for (int k = 0; k < 4; k++)
                    s = fmaf(srcP[r][k], Bm[k][c], s);
                P[r][c] = s;
            }
        float* o = wproj + (b * (VV - 1) + (v - 1)) * 12;
        for (int r = 0; r < 3; r++)
            for (int c = 0; c < 3; c++) o[r * 3 + c] = P[r][c];
        for (int r = 0; r < 3; r++) o[9 + r] = P[r][3];
        return;
    }

    __shared__ float tile[64][36];
    int vb = blockIdx.x >> 8;
    int base = (blockIdx.x & 255) * 64;
#pragma unroll
    for (int k = 0; k < 2; k++) {
        int c = (t >> 4) + 16 * k;
        int p = t & 15;
        float4 v = *(const float4*)&fea[((size_t)vb * CC + c) * HWW + base + 4 * p];
        int cs = c ^ ((p & 7) << 2);
        tile[4 * p + 0][cs] = v.x;
        tile[4 * p + 1][cs] = v.y;
        tile[4 * p + 2][cs] = v.z;
        tile[4 * p + 3][cs] = v.w;
    }
    __syncthreads();
#pragma unroll
    for (int m = 0; m < 2; m++) {
        int pl = (t >> 3) + 32 * m;
        int q = t & 7;
        int sw = ((pl >> 2) & 7) << 2;
        float4 v = *(const float4*)&tile[pl][(4 * q) ^ sw];
        *(float4*)&featT[((size_t)vb * HWW + base + pl) * CC + 4 * q] = v;
    }
}

// ---------------------------------------------------------------------------
// Kernel 2: VIEW-PARALLEL fused pipeline. Arithmetic BIT-FROZEN at r9/r10:
// thread = (pixel 0..1, view 0..3, depth 0..31); each thread runs ONE view's
// gather+corr+softmax (identical code to one r10 view-iteration); (cw, cf[8])
// go through LDS; vi==0 threads accumulate in exact view order (identical
// add sequence), then logit/final-softmax/argmax exactly as r10.
// 4x TLP, lower register pressure, NO launch-bounds pin (r12 lesson).
// ---------------------------------------------------------------------------
__global__ __launch_bounds__(256) void main_kernel(const float* __restrict__ featT,
                                                   const float* __restrict__ wproj,
                                                   const float* __restrict__ depth_hypo,
                                                   const float* __restrict__ reg_w,
                                                   float* __restrict__ out) {
#pragma clang fp contract(off)
    __shared__ float s_ref[2][32];
    __shared__ float s_e[8][32];
    __shared__ float s_f[2][32];
    __shared__ float s_acc[2][32][4][12];   // [pl][d][vi][cf0..7, cw, pad]
    __shared__ float s_proj[4][12];
    __shared__ float s_regw[8];

    int t = threadIdx.x;
    int d = t & 31;
    int vi = (t >> 5) & 3;
    int pl = t >> 7;                 // 0..1
    int grp = t >> 5;                // 0..7 (s_e row)
    int pixbase = blockIdx.x * 2;
    int b = pixbase / HWW;
    int hwb = pixbase - b * HWW;

    if (t < 64) s_ref[t >> 5][t & 31] = featT[((size_t)(b * HWW + hwb + (t >> 5))) * CC + (t & 31)];
    else if (t < 112) { int u = t - 64; s_proj[u / 12][u % 12] = wproj[b * (VV - 1) * 12 + u]; }
    else if (t < 120) s_regw[t - 112] = reg_w[t - 112];
    __syncthreads();

    int hw = hwb + pl;
    int y = hw >> 7, x = hw & (WW - 1);
    float fx = (float)x, fy = (float)y;
    float dep = depth_hypo[(size_t)(b * DD + d) * HWW + hw];

    // ---- one view's work (identical to one r10 view-iteration) ----
    const float* pr = s_proj[vi];
    float rx = fmaf(pr[1], fy, pr[0] * fx) + pr[2];
    float ry = fmaf(pr[4], fy, pr[3] * fx) + pr[5];
    float rz = fmaf(pr[7], fy, pr[6] * fx) + pr[8];
    float X = rx * dep + pr[9];
    float Y = ry * dep + pr[10];
    float Z = rz * dep + pr[11];
    if (Z == 0.f) Z = 1e-9f;
    float px = X / Z, py = Y / Z;

    float x0f = floorf(px), y0f = floorf(py);
    float x1f = x0f + 1.0f, y1f = y0f + 1.0f;
    float wx1 = px - x0f, wx0 = 1.0f - wx1;
    float wy1 = py - y0f, wy0 = 1.0f - wy1;
    bool vx0 = (x0f >= 0.f) && (x0f <= (float)(WW - 1));
    bool vx1 = (x1f >= 0.f) && (x1f <= (float)(WW - 1));
    bool vy0 = (y0f >= 0.f) && (y0f <= (float)(HH - 1));
    bool vy1 = (y1f >= 0.f) && (y1f <= (float)(HH - 1));

    int xc0 = (int)fminf(fmaxf(x0f, 0.f), (float)(WW - 1));
    int xc1 = (int)fminf(fmaxf(x1f, 0.f), (float)(WW - 1));
    int yc0 = (int)fminf(fmaxf(y0f, 0.f), (float)(HH - 1));
    int yc1 = (int)fminf(fmaxf(y1f, 0.f), (float)(HH - 1));

    float w00 = (wx0 * wy0) * ((vx0 && vy0) ? 1.f : 0.f);
    float w10 = (wx1 * wy0) * ((vx1 && vy0) ? 1.f : 0.f);
    float w01 = (wx0 * wy1) * ((vx0 && vy1) ? 1.f : 0.f);
    float w11 = (wx1 * wy1) * ((vx1 && vy1) ? 1.f : 0.f);

    const float* srcB = featT + (size_t)((vi + 1) * BB + b) * HWW * CC;
    const float4* p00 = (const float4*)(srcB + ((size_t)yc0 * WW + xc0) * CC);
    const float4* p10 = (const float4*)(srcB + ((size_t)yc0 * WW + xc1) * CC);
    const float4* p01 = (const float4*)(srcB + ((size_t)yc1 * WW + xc0) * CC);
    const float4* p11 = (const float4*)(srcB + ((size_t)yc1 * WW + xc1) * CC);

    float cf[8];
    float s = 0.f;
#pragma unroll
    for (int g = 0; g < 8; g++) {
        float4 rf = *(const float4*)&s_ref[pl][g * 4];
        float4 f00 = p00[g], f10 = p10[g], f01 = p01[g], f11 = p11[g];
        float wrp[4];
        {
            float a;
            a = f00.x * w00; a = a + f10.x * w10; a = a + f01.x * w01; a = a + f11.x * w11; wrp[0] = a;
            a = f00.y * w00; a = a + f10.y * w10; a = a + f01.y * w01; a = a + f11.y * w11; wrp[1] = a;
            a = f00.z * w00; a = a + f10.z * w10; a = a + f01.z * w01; a = a + f11.z * w11; wrp[2] = a;
            a = f00.w * w00; a = a + f10.w * w10; a = a + f01.w * w01; a = a + f11.w * w11; wrp[3] = a;
        }
        float pr0 = wrp[0] * rf.x;
        float pr1 = wrp[1] * rf.y;
        float pr2 = wrp[2] * rf.z;
        float pr3 = wrp[3] * rf.w;
        float gs = pr0;
        gs = gs + pr1; gs = gs + pr2; gs = gs + pr3;
        gs = gs * 0.25f;
        cf[g] = gs;
        s = s + gs;
    }

    // per-view softmax over d (32-lane half-wave group): max butterfly +
    // LDS round-trip sequential sum (bit-identical to r10)
    float m = s;
#pragma unroll
    for (int msk = 1; msk < 32; msk <<= 1) m = fmaxf(m, __shfl_xor(m, msk, 64));
    float e = expf(s - m);
    s_e[grp][d] = e;
    float sum = 0.f;
#pragma unroll
    for (int j = 0; j < 8; j++) {
        float4 q = *(const float4*)&s_e[grp][j * 4];
        sum = sum + q.x; sum = sum + q.y; sum = sum + q.z; sum = sum + q.w;
    }
    float cw = (e / sum) * 0.17677669529663687f;

    // publish (cf, cw)
    *(float4*)&s_acc[pl][d][vi][0] = make_float4(cf[0], cf[1], cf[2], cf[3]);
    *(float4*)&s_acc[pl][d][vi][4] = make_float4(cf[4], cf[5], cf[6], cf[7]);
    s_acc[pl][d][vi][8] = cw;
    __syncthreads();

    // ---- epilogue on vi==0 threads (lanes 0..31 of waves 0 and 2) ----
    if (vi == 0) {
        float accs[8];
#pragma unroll
        for (int g = 0; g < 8; g++) accs[g] = 0.f;
        float cws = 1e-8f;
#pragma unroll
        for (int v = 0; v < 4; v++) {
            float4 c0 = *(const float4*)&s_acc[pl][d][v][0];
            float4 c1 = *(const float4*)&s_acc[pl][d][v][4];
            float cwv = s_acc[pl][d][v][8];
            cws = cws + cwv;
            float tt;
            tt = cwv * c0.x; accs[0] = accs[0] + tt;
            tt = cwv * c0.y; accs[1] = accs[1] + tt;
            tt = cwv * c0.z; accs[2] = accs[2] + tt;
            tt = cwv * c0.w; accs[3] = accs[3] + tt;
            tt = cwv * c1.x; accs[4] = accs[4] + tt;
            tt = cwv * c1.y; accs[5] = accs[5] + tt;
            tt = cwv * c1.z; accs[6] = accs[6] + tt;
            tt = cwv * c1.w; accs[7] = accs[7] + tt;
        }

        float logit = 0.f;
#pragma unroll
        for (int g = 0; g < 8; g++) {
            float cfn = accs[g] / cws;
            logit = fmaf(s_regw[g], cfn, logit);
        }

        float m2 = logit;
#pragma unroll
        for (int msk = 1; msk < 32; msk <<= 1) m2 = fmaxf(m2, __shfl_xor(m2, msk, 64));
        float e2 = expf(logit - m2);
        s_f[pl][d] = e2;
        float s2 = 0.f;
#pragma unroll
        for (int j = 0; j < 8; j++) {
            float4 q = *(const float4*)&s_f[pl][j * 4];
            s2 = s2 + q.x; s2 = s2 + q.y; s2 = s2 + q.z; s2 = s2 + q.w;
        }
        float attn = e2 / s2;
        out[(size_t)BB * HWW + (size_t)(b * DD + d) * HWW + hw] = attn;

        // np.argmax: bitwise max + min lane holding it (lanes 0..31, base 0)
        float a1 = attn;
#pragma unroll
        for (int msk = 1; msk < 32; msk <<= 1) a1 = fmaxf(a1, __shfl_xor(a1, msk, 64));
        int idx1 = (attn == a1) ? d : 1000;
#pragma unroll
        for (int msk = 1; msk < 32; msk <<= 1) {
            int oi = __shfl_xor(idx1, msk, 64);
            idx1 = (oi < idx1) ? oi : idx1;
        }
        float dep1 = __shfl(dep, idx1, 64);
        if (d == 0) out[b * HWW + hw] = dep1;
    }
}

// ---------------------------------------------------------------------------
extern "C" void kernel_launch(void* const* d_in, const int* in_sizes, int n_in,
                              void* d_out, int out_size, void* d_ws, size_t ws_size,
                              hipStream_t stream) {
    const float* features   = (const float*)d_in[0];   // [V,B,C,H,W]
    const float* pm         = (const float*)d_in[1];   // [B,V,2,4,4]
    const float* depth_hypo = (const float*)d_in[2];   // [B,D,H,W]
    const float* reg_w      = (const float*)d_in[3];   // [G]
    float* out = (float*)d_out;                        // depth [B,H,W] ++ attn [B,D,H,W]

    float* wproj = (float*)d_ws;                       // 96 floats
    float* featT = (float*)((char*)d_ws + 4096);       // [VB,H,W,C] = 21 MB

    prep_kernel<<<TRBLOCKS + 1, 256, 0, stream>>>(features, featT, pm, wproj);
    main_kernel<<<BB * HWW / 2, 256, 0, stream>>>(featT, wproj, depth_hypo, reg_w, out);
}

// Round 14
// 151.594 us; speedup vs baseline: 3.7612x; 1.0331x over previous
//
#include <hip/hip_runtime.h>
#include <math.h>

#pragma clang fp contract(off)

#define VV 5
#define BB 2
#define CC 32
#define HH 128
#define WW 128
#define DD 32
#define GG 8
#define HWW (HH*WW)
#define TRBLOCKS (VV*BB*(HWW/64))   // 2560 transpose blocks

typedef float v2f __attribute__((ext_vector_type(2)));

// ---------------------------------------------------------------------------
// Kernel 1 (fused): transpose features [VB,C,H,W] -> [VB,H,W,C]  +  proj setup.
// (unchanged — bit-exact copy; proj math bit-frozen at r9)
// ---------------------------------------------------------------------------
__global__ __launch_bounds__(256) void prep_kernel(const float* __restrict__ fea,
                                                   float* __restrict__ featT,
                                                   const float* __restrict__ pm,
                                                   float* __restrict__ wproj) {
#pragma clang fp contract(off)
    int t = threadIdx.x;
    if (blockIdx.x == TRBLOCKS) {
        int tid = t;
        if (tid >= BB * (VV - 1)) return;
        int b = tid / (VV - 1);
        int v = tid % (VV - 1) + 1;

        float refP[4][4], srcP[4][4];
        for (int which = 0; which < 2; which++) {
            int view = (which == 0) ? 0 : v;
            const float* base = pm + (size_t)(b * VV + view) * 2 * 16;
            const float* ext  = base;
            const float* intr = base + 16;
            float (*M)[4] = (which == 0) ? refP : srcP;
            for (int r = 0; r < 3; r++)
                for (int c = 0; c < 4; c++) {
                    float s = 0.f;
                    for (int k = 0; k < 3; k++)
                        s = fmaf(intr[r * 4 + k], ext[k * 4 + c], s);  // einsum FMA chain
                    M[r][c] = s;
                }
            for (int c = 0; c < 4; c++) M[3][c] = ext[12 + c];
        }

        float A[4][4];
        for (int r = 0; r < 4; r++)
            for (int c = 0; c < 4; c++) A[r][c] = refP[r][c];
        int ipiv[4];
        for (int j = 0; j < 4; j++) {
            int p = j; float amax = fabsf(A[j][j]);
            for (int i = j + 1; i < 4; i++) {
                float tt = fabsf(A[i][j]);
                if (tt > amax) { amax = tt; p = i; }
            }
            ipiv[j] = p;
            if (p != j)
                for (int c = 0; c < 4; c++) { float tt = A[j][c]; A[j][c] = A[p][c]; A[p][c] = tt; }
            float rcp = 1.0f / A[j][j];
            for (int i = j + 1; i < 4; i++) A[i][j] = A[i][j] * rcp;
            for (int i = j + 1; i < 4; i++)
                for (int k = j + 1; k < 4; k++)
                    A[i][k] = fmaf(-A[i][j], A[j][k], A[i][k]);
        }

        float Bm[4][4];
        for (int r = 0; r < 4; r++)
            for (int c = 0; c < 4; c++) Bm[r][c] = (r == c) ? 1.f : 0.f;
        for (int j = 0; j < 4; j++) {
            int p = ipiv[j];
            if (p != j)
                for (int c = 0; c < 4; c++) { float tt = Bm[j][c]; Bm[j][c] = Bm[p][c]; Bm[p][c] = tt; }
        }
        float invd[4];
        for (int k = 0; k < 4; k++) invd[k] = 1.0f / A[k][k];
        for (int c = 0; c < 4; c++) {
            for (int k = 0; k < 4; k++)
                for (int i = k + 1; i < 4; i++)
                    Bm[i][c] = fmaf(-A[i][k], Bm[k][c], Bm[i][c]);
            for (int k = 3; k >= 0; k--) {
                Bm[k][c] = Bm[k][c] * invd[k];
                for (int i = 0; i < k; i++)
                    Bm[i][c] = fmaf(-A[i][k], Bm[k][c], Bm[i][c]);
            }
        }

        float P[3][4];
        for (int r = 0; r < 3; r++)
            for (int c = 0; c < 4; c++) {
                float s = 0.f;
                for (int k = 0; k < 4; k++)
                    s = fmaf(srcP[r][k], Bm[k][c], s);
                P[r][c] = s;
            }
        float* o = wproj + (b * (VV - 1) + (v - 1)) * 12;
        for (int r = 0; r < 3; r++)
            for (int c = 0; c < 3; c++) o[r * 3 + c] = P[r][c];
        for (int r = 0; r < 3; r++) o[9 + r] = P[r][3];
        return;
    }

    __shared__ float tile[64][36];
    int vb = blockIdx.x >> 8;
    int base = (blockIdx.x & 255) * 64;
#pragma unroll
    for (int k = 0; k < 2; k++) {
        int c = (t >> 4) + 16 * k;
        int p = t & 15;
        float4 v = *(const float4*)&fea[((size_t)vb * CC + c) * HWW + base + 4 * p];
        int cs = c ^ ((p & 7) << 2);
        tile[4 * p + 0][cs] = v.x;
        tile[4 * p + 1][cs] = v.y;
        tile[4 * p + 2][cs] = v.z;
        tile[4 * p + 3][cs] = v.w;
    }
    __syncthreads();
#pragma unroll
    for (int m = 0; m < 2; m++) {
        int pl = (t >> 3) + 32 * m;
        int q = t & 7;
        int sw = ((pl >> 2) & 7) << 2;
        float4 v = *(const float4*)&tile[pl][(4 * q) ^ sw];
        *(float4*)&featT[((size_t)vb * HWW + base + pl) * CC + 4 * q] = v;
    }
}

// ---------------------------------------------------------------------------
// Kernel 2: r10 structure (best: main 90us), correlation math in PACKED f32
// (v_pk_mul/v_pk_add via <2 x float>): per-channel op chains unchanged =>
// per-component IEEE rounding identical => bit-exact. Cross-channel sums stay
// scalar in the exact original order. No launch-bounds pin (r12 lesson).
// ---------------------------------------------------------------------------
__global__ __launch_bounds__(256) void main_kernel(const float* __restrict__ featT,
                                                   const float* __restrict__ wproj,
                                                   const float* __restrict__ depth_hypo,
                                                   const float* __restrict__ reg_w,
                                                   float* __restrict__ out) {
#pragma clang fp contract(off)
    __shared__ float s_ref[8][32];
    __shared__ float s_e[8][32];
    __shared__ float s_proj[4][12];
    __shared__ float s_regw[8];

    int t = threadIdx.x;
    int d = t & 31, pl = t >> 5;
    int base = t & 32;
    int pixbase = blockIdx.x * 8;
    int b = pixbase / HWW;
    int hwb = pixbase - b * HWW;

    s_ref[pl][d] = featT[((size_t)(b * HWW + hwb + pl)) * CC + d];
    if (t < 48) s_proj[t / 12][t % 12] = wproj[b * (VV - 1) * 12 + t];
    if (t < 8) s_regw[t] = reg_w[t];
    __syncthreads();

    int hw = hwb + pl;
    int y = hw >> 7, x = hw & (WW - 1);
    float fx = (float)x, fy = (float)y;
    float dep = depth_hypo[(size_t)(b * DD + d) * HWW + hw];

    // ref fragments as packed channel pairs (16 v2f = 32 VGPRs, same as r10)
    v2f refv[16];
#pragma unroll
    for (int g = 0; g < 8; g++) {
        float4 r = *(const float4*)&s_ref[pl][g * 4];
        refv[2 * g]     = (v2f){r.x, r.y};
        refv[2 * g + 1] = (v2f){r.z, r.w};
    }

    float accs[8];
#pragma unroll
    for (int g = 0; g < 8; g++) accs[g] = 0.f;
    float cws = 1e-8f;

    for (int vi = 0; vi < 4; vi++) {
        const float* pr = s_proj[vi];
        float rx = fmaf(pr[1], fy, pr[0] * fx) + pr[2];
        float ry = fmaf(pr[4], fy, pr[3] * fx) + pr[5];
        float rz = fmaf(pr[7], fy, pr[6] * fx) + pr[8];
        float X = rx * dep + pr[9];
        float Y = ry * dep + pr[10];
        float Z = rz * dep + pr[11];
        if (Z == 0.f) Z = 1e-9f;
        float px = X / Z, py = Y / Z;

        float x0f = floorf(px), y0f = floorf(py);
        float x1f = x0f + 1.0f, y1f = y0f + 1.0f;
        float wx1 = px - x0f, wx0 = 1.0f - wx1;
        float wy1 = py - y0f, wy0 = 1.0f - wy1;
        bool vx0 = (x0f >= 0.f) && (x0f <= (float)(WW - 1));
        bool vx1 = (x1f >= 0.f) && (x1f <= (float)(WW - 1));
        bool vy0 = (y0f >= 0.f) && (y0f <= (float)(HH - 1));
        bool vy1 = (y1f >= 0.f) && (y1f <= (float)(HH - 1));

        int xc0 = (int)fminf(fmaxf(x0f, 0.f), (float)(WW - 1));
        int xc1 = (int)fminf(fmaxf(x1f, 0.f), (float)(WW - 1));
        int yc0 = (int)fminf(fmaxf(y0f, 0.f), (float)(HH - 1));
        int yc1 = (int)fminf(fmaxf(y1f, 0.f), (float)(HH - 1));

        float w00 = (wx0 * wy0) * ((vx0 && vy0) ? 1.f : 0.f);
        float w10 = (wx1 * wy0) * ((vx1 && vy0) ? 1.f : 0.f);
        float w01 = (wx0 * wy1) * ((vx0 && vy1) ? 1.f : 0.f);
        float w11 = (wx1 * wy1) * ((vx1 && vy1) ? 1.f : 0.f);

        v2f w00v = (v2f){w00, w00};
        v2f w10v = (v2f){w10, w10};
        v2f w01v = (v2f){w01, w01};
        v2f w11v = (v2f){w11, w11};

        const float* srcB = featT + (size_t)((vi + 1) * BB + b) * HWW * CC;
        const float4* p00 = (const float4*)(srcB + ((size_t)yc0 * WW + xc0) * CC);
        const float4* p10 = (const float4*)(srcB + ((size_t)yc0 * WW + xc1) * CC);
        const float4* p01 = (const float4*)(srcB + ((size_t)yc1 * WW + xc0) * CC);
        const float4* p11 = (const float4*)(srcB + ((size_t)yc1 * WW + xc1) * CC);

        float cf[8];
        float s = 0.f;
#pragma unroll
        for (int g = 0; g < 8; g++) {
            float4 f00 = p00[g], f10 = p10[g], f01 = p01[g], f11 = p11[g];
            v2f f00l = (v2f){f00.x, f00.y}, f00h = (v2f){f00.z, f00.w};
            v2f f10l = (v2f){f10.x, f10.y}, f10h = (v2f){f10.z, f10.w};
            v2f f01l = (v2f){f01.x, f01.y}, f01h = (v2f){f01.z, f01.w};
            v2f f11l = (v2f){f11.x, f11.y}, f11h = (v2f){f11.z, f11.w};

            // warped = ((t00*w00 + t10*w10) + t01*w01) + t11*w11, per channel;
            // packed pairs, separate mul/add (contract off) — bit-exact per lane
            v2f a = f00l * w00v;
            a = a + f10l * w10v;
            a = a + f01l * w01v;
            a = a + f11l * w11v;
            v2f bq = f00h * w00v;
            bq = bq + f10h * w10v;
            bq = bq + f01h * w01v;
            bq = bq + f11h * w11v;

            v2f prl = a * refv[2 * g];
            v2f prh = bq * refv[2 * g + 1];

            // gs = ((pr0 + pr1) + pr2) + pr3  (exact original order)
            float gs = prl.x;
            gs = gs + prl.y; gs = gs + prh.x; gs = gs + prh.y;
            gs = gs * 0.25f;
            cf[g] = gs;
            s = s + gs;
        }

        // softmax over d: max butterfly (order-free), denominator via LDS
        // round-trip + SAME sequential d-order adds (bit-identical).
        float m = s;
#pragma unroll
        for (int msk = 1; msk < 32; msk <<= 1) m = fmaxf(m, __shfl_xor(m, msk, 64));
        float e = expf(s - m);
        s_e[pl][d] = e;
        float sum = 0.f;
#pragma unroll
        for (int j = 0; j < 8; j++) {
            float4 q = *(const float4*)&s_e[pl][j * 4];
            sum = sum + q.x; sum = sum + q.y; sum = sum + q.z; sum = sum + q.w;
        }
        float cw = (e / sum) * 0.17677669529663687f;

        cws = cws + cw;
#pragma unroll
        for (int g = 0; g < 8; g++) {
            float tterm = cw * cf[g];
            accs[g] = accs[g] + tterm;
        }
    }

    // logit: elementwise /cws then einsum FMA chain over g
    float logit = 0.f;
#pragma unroll
    for (int g = 0; g < 8; g++) {
        float cfn = accs[g] / cws;
        logit = fmaf(s_regw[g], cfn, logit);
    }

    // final softmax over d (same LDS pattern)
    float m2 = logit;
#pragma unroll
    for (int msk = 1; msk < 32; msk <<= 1) m2 = fmaxf(m2, __shfl_xor(m2, msk, 64));
    float e2 = expf(logit - m2);
    s_e[pl][d] = e2;
    float s2 = 0.f;
#pragma unroll
    for (int j = 0; j < 8; j++) {
        float4 q = *(const float4*)&s_e[pl][j * 4];
        s2 = s2 + q.x; s2 = s2 + q.y; s2 = s2 + q.z; s2 = s2 + q.w;
    }
    float attn = e2 / s2;
    out[(size_t)BB * HWW + (size_t)(b * DD + d) * HWW + hw] = attn;

    // np.argmax: bitwise max (butterfly) + min lane holding it
    float a1 = attn;
#pragma unroll
    for (int msk = 1; msk < 32; msk <<= 1) a1 = fmaxf(a1, __shfl_xor(a1, msk, 64));
    int idx1 = (attn == a1) ? d : 1000;
#pragma unroll
    for (int msk = 1; msk < 32; msk <<= 1) {
        int oi = __shfl_xor(idx1, msk, 64);
        idx1 = (oi < idx1) ? oi : idx1;
    }
    float dep1 = __shfl(dep, base + idx1, 64);
    if (d == 0) out[b * HWW + hw] = dep1;
}

// ---------------------------------------------------------------------------
extern "C" void kernel_launch(void* const* d_in, const int* in_sizes, int n_in,
                              void* d_out, int out_size, void* d_ws, size_t ws_size,
                              hipStream_t stream) {
    const float* features   = (const float*)d_in[0];   // [V,B,C,H,W]
    const float* pm         = (const float*)d_in[1];   // [B,V,2,4,4]
    const float* depth_hypo = (const float*)d_in[2];   // [B,D,H,W]
    const float* reg_w      = (const float*)d_in[3];   // [G]
    float* out = (float*)d_out;                        // depth [B,H,W] ++ attn [B,D,H,W]

    float* wproj = (float*)d_ws;                       // 96 floats
    float* featT = (float*)((char*)d_ws + 4096);       // [VB,H,W,C] = 21 MB

    prep_kernel<<<TRBLOCKS + 1, 256, 0, stream>>>(features, featT, pm, wproj);
    main_kernel<<<BB * HWW / 8, 256, 0, stream>>>(featT, wproj, depth_hypo, reg_w, out);
}